// Round 9
// baseline (462.390 us; speedup 1.0000x reference)
//
#include <hip/hip_runtime.h>

#define NN 50000
#define NE 800000
#define DD 128
#define NPAD 50176          // 196*256, padded scan domain
#define NBLK_SCAN 196       // NPAD/256

typedef __attribute__((ext_vector_type(8))) short short8;
typedef __attribute__((ext_vector_type(4))) float f32x4;

static __device__ __forceinline__ float b2f_lo(unsigned u) {
    return __builtin_bit_cast(float, u << 16);
}
static __device__ __forceinline__ float b2f_hi(unsigned u) {
    return __builtin_bit_cast(float, u & 0xffff0000u);
}
static __device__ __forceinline__ unsigned short f2b(float f) {
    unsigned u = __builtin_bit_cast(unsigned, f);
    u += 0x7FFFu + ((u >> 16) & 1u);          // round-to-nearest-even
    return (unsigned short)(u >> 16);
}

// ---------------------------------------------------------------------------
// dst-sort machinery
// ---------------------------------------------------------------------------
__global__ __launch_bounds__(256) void k_hist(
    const int* __restrict__ edst, int* __restrict__ cnt)
{
    const int e = blockIdx.x * 256 + threadIdx.x;
    atomicAdd(&cnt[edst[e]], 1);
}

__global__ __launch_bounds__(256) void k_scan_a(
    const int* __restrict__ cnt, int* __restrict__ bsum)
{
    __shared__ int s[256];
    const int t = threadIdx.x;
    s[t] = cnt[blockIdx.x * 256 + t];
    __syncthreads();
    for (int d = 128; d > 0; d >>= 1) {
        if (t < d) s[t] += s[t + d];
        __syncthreads();
    }
    if (t == 0) bsum[blockIdx.x] = s[0];
}

__global__ __launch_bounds__(256) void k_scan_b(int* __restrict__ bsum)
{
    __shared__ int s[256];
    const int t = threadIdx.x;
    s[t] = (t < NBLK_SCAN) ? bsum[t] : 0;
    __syncthreads();
    for (int d = 1; d < 256; d <<= 1) {
        int v = (t >= d) ? s[t - d] : 0;
        __syncthreads();
        s[t] += v;
        __syncthreads();
    }
    bsum[t] = (t == 0) ? 0 : s[t - 1];
}

__global__ __launch_bounds__(256) void k_scan_c(
    const int* __restrict__ cnt, const int* __restrict__ bsum,
    int* __restrict__ off, int* __restrict__ cur)
{
    __shared__ int s[256];
    const int t = threadIdx.x;
    const int i = blockIdx.x * 256 + t;
    const int c = cnt[i];
    s[t] = c;
    __syncthreads();
    for (int d = 1; d < 256; d <<= 1) {
        int v = (t >= d) ? s[t - d] : 0;
        __syncthreads();
        s[t] += v;
        __syncthreads();
    }
    const int ex = bsum[blockIdx.x] + s[t] - c;
    off[i] = ex;
    cur[i] = ex;
}

// packed record: {src, typ, norm_bits, dst}
__global__ __launch_bounds__(256) void k_scatter(
    const int* __restrict__ esrc, const int* __restrict__ edst,
    const int* __restrict__ etyp, const float* __restrict__ enorm,
    int* __restrict__ cur, int4* __restrict__ sedge)
{
    const int e = blockIdx.x * 256 + threadIdx.x;
    const int d = edst[e];
    const int pos = atomicAdd(&cur[d], 1);
    sedge[pos] = make_int4(esrc[e], etyp[e],
                           __builtin_bit_cast(int, enorm[e]), d);
}

// ---------------------------------------------------------------------------
// Conversions
// ---------------------------------------------------------------------------
// X1[n][0:128]=bf16(h); X1[n][128:256]=bf16(fprev*d); X2[n][128:256]=bf16(sprev*d)
__global__ __launch_bounds__(256) void conv_x(
    const float* __restrict__ x, const float* __restrict__ fprev,
    const float* __restrict__ sprev, const float* __restrict__ tdiff,
    unsigned short* __restrict__ X1, unsigned short* __restrict__ X2)
{
    const int idx = blockIdx.x * 256 + threadIdx.x;   // NN*128 threads
    const int n = idx >> 7, j = idx & 127;
    const float d = __expf(-tdiff[n] * 0.1f);
    X1[(size_t)n * 256 + j]       = f2b(x[(size_t)n * 128 + j]);
    X1[(size_t)n * 256 + 128 + j] = f2b(fprev[(size_t)n * 128 + j] * d);
    X2[(size_t)n * 256 + 128 + j] = f2b(sprev[(size_t)n * 128 + j] * d);
}

// Fused: W1/W2 fp32->bf16 (blocks 0..1839) + MFMA B-fragment pack (blocks 1840..1871)
__global__ __launch_bounds__(256) void k_wprep(
    const float* __restrict__ W1, const float* __restrict__ W2,
    unsigned short* __restrict__ W1b, unsigned short* __restrict__ W2b,
    const float* __restrict__ lw1, const float* __restrict__ tw1,
    const float* __restrict__ lw2, const float* __restrict__ tw2,
    unsigned short* __restrict__ Wp1, unsigned short* __restrict__ Wp2)
{
    const int gb = blockIdx.x;
    if (gb < 1840) {
        const int i = gb * 256 + threadIdx.x;
        if (i < 460 * 512) W1b[i] = f2b(W1[i]);
        else               W2b[i - 460 * 512] = f2b(W2[i - 460 * 512]);
    } else {
        const int g = (gb - 1840) * 256 + threadIdx.x;  // 8192
        const int c = g & 4095;
        const float* lw = (g < 4096) ? lw1 : lw2;
        const float* tw = (g < 4096) ? tw1 : tw2;
        unsigned short* Wp = (g < 4096) ? Wp1 : Wp2;
        const int ct = c >> 9, ks = (c >> 6) & 7, lane = c & 63;
        const int col = ct * 16 + (lane & 15);
        unsigned short* o = Wp + (size_t)c * 8;
        #pragma unroll
        for (int i = 0; i < 8; ++i) {
            const int k = ks * 32 + (lane >> 4) * 8 + i;
            const float v = (k < 128) ? lw[(size_t)k * 128 + col]
                                      : tw[(size_t)(k - 128) * 128 + col];
            o[i] = f2b(v);
        }
    }
}

// ---------------------------------------------------------------------------
// per-edge aggregation step (round-6 proven): lane l handles k in {2l,2l+1}.
// 1 dwordx4 meta (scalarized), 1 dword h (coalesced row), 1 dwordx4 W.
// ---------------------------------------------------------------------------
__device__ __forceinline__ void agg_edge(
    const unsigned short* __restrict__ x,
    const unsigned short* __restrict__ Wb,
    const int4* __restrict__ sedge, int i,
    int woff, int l, float4& acc)
{
    const int4 e = sedge[i];
    const int src = __builtin_amdgcn_readfirstlane(e.x);
    const int typ = __builtin_amdgcn_readfirstlane(e.y);
    const float nr = __builtin_bit_cast(float, __builtin_amdgcn_readfirstlane(e.z));
    const unsigned hw = ((const unsigned*)(x + (size_t)src * 256))[l];
    const uint4 wv = *(const uint4*)(Wb + (size_t)typ * 512 + woff);
    const float h0 = b2f_lo(hw) * nr;
    const float h1 = b2f_hi(hw) * nr;
    acc.x += h0 * b2f_lo(wv.x) + h1 * b2f_lo(wv.z);
    acc.y += h0 * b2f_hi(wv.x) + h1 * b2f_hi(wv.z);
    acc.z += h0 * b2f_lo(wv.y) + h1 * b2f_lo(wv.w);
    acc.w += h0 * b2f_hi(wv.y) + h1 * b2f_hi(wv.w);
}

// ---------------------------------------------------------------------------
// Fused layer kernel: block = 64 nodes.
//  phase 1: aggregate (wave = 16 nodes, k_agg2 inner loop) -> LDS cs, *nnorm
//  phase 2: MFMA GEMM (X @ [lw;tw]) + agg from LDS, relu, coalesced store,
//           optional bf16 copy into Xnext left half.
// agg NEVER touches global memory (saves 51.2 MB round-trip/layer + a
// dispatch boundary vs separate k_agg2 + combine_mfma).
// ---------------------------------------------------------------------------
template<int ACT, int WRITE_NEXT>
__global__ __launch_bounds__(256) void layer_fused(
    const unsigned short* __restrict__ X,     // [NN,256] bf16
    const int4*  __restrict__ sedge,
    const int*   __restrict__ off,
    const unsigned short* __restrict__ Wb,    // [460,512] bf16
    const unsigned short* __restrict__ Wp,    // packed GEMM B, 64KB
    const float* __restrict__ nnorm,
    float* __restrict__ out,                  // [NN,128]
    unsigned short* __restrict__ Xnext)       // [NN,256] bf16 or nullptr
{
    const int t = threadIdx.x;
    const int l = t & 63;
    const int w = t >> 6;
    const int nodebase = blockIdx.x * 64;

    __shared__ float cs[64][132];

    // ---------------- phase 1: aggregate 16 nodes per wave ----------------
    const int woff = (l >> 1) * 16 + (l & 1) * 8;   // ushort offset in W row
    const int cofs = (l >> 1) * 4 + (l & 1) * 2;    // this lane's 2 output cols

    for (int m = 0; m < 16; ++m) {
        const int ln = w * 16 + m;
        const int n  = nodebase + ln;
        if (n < NN) {
            const int beg = off[n], end = off[n + 1];
            float4 a0 = {0,0,0,0}, a1 = {0,0,0,0}, a2 = {0,0,0,0}, a3 = {0,0,0,0};
            int i = beg;
            for (; i + 4 <= end; i += 4) {
                agg_edge(X, Wb, sedge, i,     woff, l, a0);
                agg_edge(X, Wb, sedge, i + 1, woff, l, a1);
                agg_edge(X, Wb, sedge, i + 2, woff, l, a2);
                agg_edge(X, Wb, sedge, i + 3, woff, l, a3);
            }
            for (; i < end; ++i) agg_edge(X, Wb, sedge, i, woff, l, a0);

            float4 s;
            s.x = (a0.x + a1.x) + (a2.x + a3.x);
            s.y = (a0.y + a1.y) + (a2.y + a3.y);
            s.z = (a0.z + a1.z) + (a2.z + a3.z);
            s.w = (a0.w + a1.w) + (a2.w + a3.w);
            s.x += __shfl_xor(s.x, 1);
            s.y += __shfl_xor(s.y, 1);
            s.z += __shfl_xor(s.z, 1);
            s.w += __shfl_xor(s.w, 1);

            const float nn = nnorm[n];
            const float e0 = ((l & 1) ? s.z : s.x) * nn;
            const float e1 = ((l & 1) ? s.w : s.y) * nn;
            *(float2*)&cs[ln][cofs] = make_float2(e0, e1);
        } else {
            *(float2*)&cs[ln][cofs] = make_float2(0.f, 0.f);
        }
    }
    __syncthreads();

    // ---------------- phase 2: MFMA GEMM + agg add ----------------
    const int wr = w >> 1, wc = w & 1;
    const int l15 = l & 15, lhi = l >> 4;
    const int rowbase = nodebase + wr * 32;

    f32x4 acc[2][4] = {};

    const int ar0 = min(rowbase + l15, NN - 1);
    const int ar1 = min(rowbase + 16 + l15, NN - 1);
    const unsigned short* a0p = X + (size_t)ar0 * 256 + lhi * 8;
    const unsigned short* a1p = X + (size_t)ar1 * 256 + lhi * 8;
    const unsigned short* bp  = Wp + (size_t)(wc * 4) * 8 * 512 + (size_t)l * 8;

    #pragma unroll
    for (int ks = 0; ks < 8; ++ks) {
        const short8 a0 = *(const short8*)(a0p + ks * 32);
        const short8 a1 = *(const short8*)(a1p + ks * 32);
        #pragma unroll
        for (int ct = 0; ct < 4; ++ct) {
            const short8 b = *(const short8*)(bp + (size_t)(ct * 8 + ks) * 512);
            acc[0][ct] = __builtin_amdgcn_mfma_f32_16x16x32_bf16(a0, b, acc[0][ct], 0, 0, 0);
            acc[1][ct] = __builtin_amdgcn_mfma_f32_16x16x32_bf16(a1, b, acc[1][ct], 0, 0, 0);
        }
    }

    // add agg from LDS in C-fragment layout (2-way bank alias: free)
    #pragma unroll
    for (int rg = 0; rg < 2; ++rg)
        #pragma unroll
        for (int ct = 0; ct < 4; ++ct)
            #pragma unroll
            for (int q = 0; q < 4; ++q)
                acc[rg][ct][q] += cs[wr * 32 + rg * 16 + lhi * 4 + q]
                                    [wc * 64 + ct * 16 + l15];
    __syncthreads();

    // overwrite cs with final values (C-layout positions)
    #pragma unroll
    for (int rg = 0; rg < 2; ++rg)
        #pragma unroll
        for (int ct = 0; ct < 4; ++ct)
            #pragma unroll
            for (int q = 0; q < 4; ++q)
                cs[wr * 32 + rg * 16 + lhi * 4 + q][wc * 64 + ct * 16 + l15]
                    = acc[rg][ct][q];
    __syncthreads();

    // coalesced epilogue: thread = (row r, 4-col strip s)
    const int r = t >> 2;
    const int s = t & 3;
    const int grow = nodebase + r;
    if (grow < NN) {
        float* outr = out + (size_t)grow * DD;
        #pragma unroll
        for (int i = 0; i < 8; ++i) {
            const int c = s * 4 + i * 16;
            float4 v = *(const float4*)&cs[r][c];
            if (ACT) {
                v.x = fmaxf(v.x, 0.f); v.y = fmaxf(v.y, 0.f);
                v.z = fmaxf(v.z, 0.f); v.w = fmaxf(v.w, 0.f);
            }
            *(float4*)(outr + c) = v;
            if (WRITE_NEXT) {
                ushort4 u;
                u.x = f2b(v.x); u.y = f2b(v.y); u.z = f2b(v.z); u.w = f2b(v.w);
                *(ushort4*)(Xnext + (size_t)grow * 256 + c) = u;
            }
        }
    }
}

// ---------------------------------------------------------------------------
// Tier-2/3 fallback kernels
// ---------------------------------------------------------------------------
__device__ __forceinline__ float pick4(float4 v, int o) {
    float a = (o & 1) ? v.y : v.x;
    float b = (o & 1) ? v.w : v.z;
    return (o & 2) ? b : a;
}

__global__ __launch_bounds__(256) void k_agg_t2(
    const float* __restrict__ x, const int4* __restrict__ sedge,
    const int* __restrict__ off, const float* __restrict__ W,
    float* __restrict__ agg)
{
    const int lane = threadIdx.x & 63;
    const int n    = blockIdx.x * 4 + (threadIdx.x >> 6);
    const int beg = off[n], end = off[n + 1];
    float4 acca = make_float4(0.f, 0.f, 0.f, 0.f);
    float4 accb = make_float4(0.f, 0.f, 0.f, 0.f);
    for (int i = beg; i < end; ++i) {
        const int4 e = sedge[i];
        const float nr = __builtin_bit_cast(float, e.z);
        const float* wr = W + (size_t)e.y * 512 + 4 * lane;
        const float4 wa = *(const float4*)wr;
        const float4 wb = *(const float4*)(wr + 256);
        const float* hr = x + (size_t)e.x * DD;
        const float ha = hr[lane] * nr;
        const float hb = hr[64 + lane] * nr;
        acca.x += ha * wa.x; acca.y += ha * wa.y; acca.z += ha * wa.z; acca.w += ha * wa.w;
        accb.x += hb * wb.x; accb.y += hb * wb.y; accb.z += hb * wb.z; accb.w += hb * wb.w;
    }
    #pragma unroll
    for (int d = 1; d <= 2; d <<= 1) {
        acca.x += __shfl_xor(acca.x, d); acca.y += __shfl_xor(acca.y, d);
        acca.z += __shfl_xor(acca.z, d); acca.w += __shfl_xor(acca.w, d);
        accb.x += __shfl_xor(accb.x, d); accb.y += __shfl_xor(accb.y, d);
        accb.z += __shfl_xor(accb.z, d); accb.w += __shfl_xor(accb.w, d);
    }
    const int o = lane & 3;
    agg[(size_t)n * DD + lane]      = pick4(acca, o);
    agg[(size_t)n * DD + 64 + lane] = pick4(accb, o);
}

__global__ __launch_bounds__(256) void edge_msg(
    const float* __restrict__ x, const int* __restrict__ esrc,
    const int* __restrict__ edst, const int* __restrict__ etyp,
    const float* __restrict__ enorm, const float* __restrict__ W,
    float* __restrict__ agg)
{
    const int t  = threadIdx.x;
    const int le = t >> 7;
    const int j  = t & 127;
    const int e  = blockIdx.x * 2 + le;
    __shared__ float sh[2][DD];
    sh[le][j] = x[(size_t)esrc[e] * DD + j];
    __syncthreads();
    const int b = j >> 2, o = j & 3;
    const float* wr = W + (size_t)etyp[e] * 512 + b * 16 + o;
    const float4 hv = *(const float4*)&sh[le][b * 4];
    float m = hv.x * wr[0] + hv.y * wr[4] + hv.z * wr[8] + hv.w * wr[12];
    m *= enorm[e];
    atomicAdd(&agg[(size_t)edst[e] * DD + j], m);
}

template<int ACT>
__global__ __launch_bounds__(256) void combine(
    float* __restrict__ out, const float* __restrict__ x,
    const float* __restrict__ prev, const float* __restrict__ tdiff,
    const float* __restrict__ nnorm, const float* __restrict__ lw,
    const float* __restrict__ tw)
{
    const int t = threadIdx.x;
    const int j = t & 127;
    const int r = t >> 7;
    const int base = blockIdx.x * 8;
    __shared__ float sh[8][DD];
    __shared__ float sp[8][DD];
    #pragma unroll
    for (int q = 0; q < 4; ++q) {
        const int m = q * 2 + r;
        const int n = base + m;
        const float decay = __expf(-tdiff[n] * 0.1f);
        sh[m][j] = x[(size_t)n * DD + j];
        sp[m][j] = prev[(size_t)n * DD + j] * decay;
    }
    __syncthreads();
    float acc[4] = {0.f, 0.f, 0.f, 0.f};
    for (int k = 0; k < DD; k += 4) {
        float wl[4], wt[4];
        #pragma unroll
        for (int kk = 0; kk < 4; ++kk) {
            wl[kk] = lw[(size_t)(k + kk) * DD + j];
            wt[kk] = tw[(size_t)(k + kk) * DD + j];
        }
        #pragma unroll
        for (int q = 0; q < 4; ++q) {
            const int m = q * 2 + r;
            const float4 a = *(const float4*)&sh[m][k];
            const float4 p = *(const float4*)&sp[m][k];
            acc[q] += a.x * wl[0] + a.y * wl[1] + a.z * wl[2] + a.w * wl[3]
                    + p.x * wt[0] + p.y * wt[1] + p.z * wt[2] + p.w * wt[3];
        }
    }
    #pragma unroll
    for (int q = 0; q < 4; ++q) {
        const int m = q * 2 + r;
        const int n = base + m;
        float v = out[(size_t)n * DD + j] * nnorm[n] + acc[q];
        if (ACT) v = fmaxf(v, 0.f);
        out[(size_t)n * DD + j] = v;
    }
}

// ---------------------------------------------------------------------------
extern "C" void kernel_launch(void* const* d_in, const int* in_sizes, int n_in,
                              void* d_out, int out_size, void* d_ws, size_t ws_size,
                              hipStream_t stream) {
    const float* h     = (const float*)d_in[0];
    const float* fprev = (const float*)d_in[1];
    const float* sprev = (const float*)d_in[2];
    const float* tdiff = (const float*)d_in[3];
    const int*   esrc  = (const int*)d_in[4];
    const int*   edst  = (const int*)d_in[5];
    const int*   etyp  = (const int*)d_in[6];
    const float* enorm = (const float*)d_in[7];
    const float* nnorm = (const float*)d_in[8];
    const float* W1    = (const float*)d_in[9];
    const float* W2    = (const float*)d_in[10];
    const float* lw1   = (const float*)d_in[11];
    const float* lw2   = (const float*)d_in[12];
    const float* tw1   = (const float*)d_in[13];
    const float* tw2   = (const float*)d_in[14];

    float* h1 = (float*)d_out;
    float* h2 = h1 + (size_t)NN * DD;
    const size_t layer_bytes = (size_t)NN * DD * sizeof(float);

    // ---- carve workspace ----
    char* wsp = (char*)d_ws;
    int*   cnt   = (int*)wsp;  wsp += (size_t)NPAD * 4;
    int*   off   = (int*)wsp;  wsp += (size_t)NPAD * 4;
    int*   cur   = (int*)wsp;  wsp += (size_t)NPAD * 4;
    int*   bsum  = (int*)wsp;  wsp += 256 * 4;
    int4*  sedge = (int4*)wsp; wsp += (size_t)NE * 16;
    const size_t ws_sorted = (size_t)(wsp - (char*)d_ws);
    unsigned short* X1   = (unsigned short*)wsp; wsp += (size_t)NN * 256 * 2;
    unsigned short* X2   = (unsigned short*)wsp; wsp += (size_t)NN * 256 * 2;
    unsigned short* Wc1p = (unsigned short*)wsp; wsp += 4096 * 8 * 2;
    unsigned short* Wc2p = (unsigned short*)wsp; wsp += 4096 * 8 * 2;
    unsigned short* W1b  = (unsigned short*)wsp; wsp += (size_t)460 * 512 * 2;
    unsigned short* W2b  = (unsigned short*)wsp; wsp += (size_t)460 * 512 * 2;
    const size_t ws_full = (size_t)(wsp - (char*)d_ws);

    const int grid_mm = (NN + 63) / 64;     // 782

    if (ws_size >= ws_full) {
        // ---- dst-sort (shared by both layers) ----
        hipMemsetAsync(cnt, 0, (size_t)NPAD * 4, stream);
        k_hist   <<<NE / 256, 256, 0, stream>>>(edst, cnt);
        k_scan_a <<<NBLK_SCAN, 256, 0, stream>>>(cnt, bsum);
        k_scan_b <<<1, 256, 0, stream>>>(bsum);
        k_scan_c <<<NBLK_SCAN, 256, 0, stream>>>(cnt, bsum, off, cur);
        k_scatter<<<NE / 256, 256, 0, stream>>>(esrc, edst, etyp, enorm, cur, sedge);
        // ---- conversions ----
        conv_x <<<NN * DD / 256, 256, 0, stream>>>(h, fprev, sprev, tdiff, X1, X2);
        k_wprep<<<1872, 256, 0, stream>>>(W1, W2, W1b, W2b,
                                          lw1, tw1, lw2, tw2, Wc1p, Wc2p);
        // ---- layer 1 (agg + GEMM fused) ----
        layer_fused<0, 1><<<grid_mm, 256, 0, stream>>>(
            X1, sedge, off, W1b, Wc1p, nnorm, h1, X2);
        // ---- layer 2 ----
        layer_fused<1, 0><<<grid_mm, 256, 0, stream>>>(
            X2, sedge, off, W2b, Wc2p, nnorm, h2, nullptr);
    } else if (ws_size >= ws_sorted) {
        // tier 2: fp32 sorted path
        hipMemsetAsync(cnt, 0, (size_t)NPAD * 4, stream);
        k_hist   <<<NE / 256, 256, 0, stream>>>(edst, cnt);
        k_scan_a <<<NBLK_SCAN, 256, 0, stream>>>(cnt, bsum);
        k_scan_b <<<1, 256, 0, stream>>>(bsum);
        k_scan_c <<<NBLK_SCAN, 256, 0, stream>>>(cnt, bsum, off, cur);
        k_scatter<<<NE / 256, 256, 0, stream>>>(esrc, edst, etyp, enorm, cur, sedge);
        k_agg_t2<<<NN / 4, 256, 0, stream>>>(h, sedge, off, W1, h1);
        combine<0><<<NN / 8, 256, 0, stream>>>(h1, h, fprev, tdiff, nnorm, lw1, tw1);
        k_agg_t2<<<NN / 4, 256, 0, stream>>>(h1, sedge, off, W2, h2);
        combine<1><<<NN / 8, 256, 0, stream>>>(h2, h1, sprev, tdiff, nnorm, lw2, tw2);
    } else {
        // tier 3: atomic path
        hipMemsetAsync(h1, 0, layer_bytes, stream);
        edge_msg<<<NE / 2, 256, 0, stream>>>(h, esrc, edst, etyp, enorm, W1, h1);
        combine<0><<<NN / 8, 256, 0, stream>>>(h1, h, fprev, tdiff, nnorm, lw1, tw1);
        hipMemsetAsync(h2, 0, layer_bytes, stream);
        edge_msg<<<NE / 2, 256, 0, stream>>>(h1, esrc, edst, etyp, enorm, W2, h2);
        combine<1><<<NN / 8, 256, 0, stream>>>(h2, h1, sprev, tdiff, nnorm, lw2, tw2);
    }
}

// Round 10
// 423.084 us; speedup vs baseline: 1.0929x; 1.0929x over previous
//
#include <hip/hip_runtime.h>

#define NN 50000
#define NE 800000
#define DD 128
#define NPAD 50176          // 196*256, padded scan domain
#define NBLK_SCAN 196       // NPAD/256

typedef __attribute__((ext_vector_type(8))) short short8;
typedef __attribute__((ext_vector_type(4))) float f32x4;

static __device__ __forceinline__ float b2f_lo(unsigned u) {
    return __builtin_bit_cast(float, u << 16);
}
static __device__ __forceinline__ float b2f_hi(unsigned u) {
    return __builtin_bit_cast(float, u & 0xffff0000u);
}
static __device__ __forceinline__ unsigned short f2b(float f) {
    unsigned u = __builtin_bit_cast(unsigned, f);
    u += 0x7FFFu + ((u >> 16) & 1u);          // round-to-nearest-even
    return (unsigned short)(u >> 16);
}
static __device__ __forceinline__ ushort4 f2b4(float4 v) {
    ushort4 u;
    u.x = f2b(v.x); u.y = f2b(v.y); u.z = f2b(v.z); u.w = f2b(v.w);
    return u;
}

// ---------------------------------------------------------------------------
// dst-sort machinery
// ---------------------------------------------------------------------------
__global__ __launch_bounds__(256) void k_hist(
    const int* __restrict__ edst, int* __restrict__ cnt)
{
    const int e = blockIdx.x * 256 + threadIdx.x;
    atomicAdd(&cnt[edst[e]], 1);
}

__global__ __launch_bounds__(256) void k_scan_a(
    const int* __restrict__ cnt, int* __restrict__ bsum)
{
    __shared__ int s[256];
    const int t = threadIdx.x;
    s[t] = cnt[blockIdx.x * 256 + t];
    __syncthreads();
    for (int d = 128; d > 0; d >>= 1) {
        if (t < d) s[t] += s[t + d];
        __syncthreads();
    }
    if (t == 0) bsum[blockIdx.x] = s[0];
}

__global__ __launch_bounds__(256) void k_scan_b(int* __restrict__ bsum)
{
    __shared__ int s[256];
    const int t = threadIdx.x;
    s[t] = (t < NBLK_SCAN) ? bsum[t] : 0;
    __syncthreads();
    for (int d = 1; d < 256; d <<= 1) {
        int v = (t >= d) ? s[t - d] : 0;
        __syncthreads();
        s[t] += v;
        __syncthreads();
    }
    bsum[t] = (t == 0) ? 0 : s[t - 1];
}

__global__ __launch_bounds__(256) void k_scan_c(
    const int* __restrict__ cnt, const int* __restrict__ bsum,
    int* __restrict__ off, int* __restrict__ cur)
{
    __shared__ int s[256];
    const int t = threadIdx.x;
    const int i = blockIdx.x * 256 + t;
    const int c = cnt[i];
    s[t] = c;
    __syncthreads();
    for (int d = 1; d < 256; d <<= 1) {
        int v = (t >= d) ? s[t - d] : 0;
        __syncthreads();
        s[t] += v;
        __syncthreads();
    }
    const int ex = bsum[blockIdx.x] + s[t] - c;
    off[i] = ex;
    cur[i] = ex;
}

// packed record: {src, typ, norm_bits, dst}
__global__ __launch_bounds__(256) void k_scatter(
    const int* __restrict__ esrc, const int* __restrict__ edst,
    const int* __restrict__ etyp, const float* __restrict__ enorm,
    int* __restrict__ cur, int4* __restrict__ sedge)
{
    const int e = blockIdx.x * 256 + threadIdx.x;
    const int d = edst[e];
    const int pos = atomicAdd(&cur[d], 1);
    sedge[pos] = make_int4(esrc[e], etyp[e],
                           __builtin_bit_cast(int, enorm[e]), d);
}

// ---------------------------------------------------------------------------
// Fused prep kernel (vectorized x4):
//  blocks [0,6250):        X conversion — X1[n][0:128]=bf16(h),
//                          X1[n][128:256]=bf16(fprev*d), X2[n][128:256]=bf16(sprev*d)
//  blocks [6250,6710):     W1/W2 fp32 -> bf16 (4 elems/thread)
//  blocks [6710,6742):     MFMA B-fragment pack of [lw;tw] for both layers
// ---------------------------------------------------------------------------
#define PREP_X_BLOCKS 6250      // NN*128/4/256
#define PREP_W_BLOCKS 460       // 2*460*512/4/256
#define PREP_BLOCKS   (PREP_X_BLOCKS + PREP_W_BLOCKS + 32)

__global__ __launch_bounds__(256) void k_prep(
    const float* __restrict__ x, const float* __restrict__ fprev,
    const float* __restrict__ sprev, const float* __restrict__ tdiff,
    unsigned short* __restrict__ X1, unsigned short* __restrict__ X2,
    const float* __restrict__ W1, const float* __restrict__ W2,
    unsigned short* __restrict__ W1b, unsigned short* __restrict__ W2b,
    const float* __restrict__ lw1, const float* __restrict__ tw1,
    const float* __restrict__ lw2, const float* __restrict__ tw2,
    unsigned short* __restrict__ Wp1, unsigned short* __restrict__ Wp2)
{
    const int gb = blockIdx.x;
    const int t  = threadIdx.x;
    if (gb < PREP_X_BLOCKS) {
        const int idx = gb * 256 + t;          // 1.6M threads, 4 cols each
        const int n = idx >> 5, j = (idx & 31) * 4;
        const float dk = __expf(-tdiff[n] * 0.1f);
        const float4 a = *(const float4*)(x     + (size_t)n * 128 + j);
        float4 b = *(const float4*)(fprev + (size_t)n * 128 + j);
        float4 c = *(const float4*)(sprev + (size_t)n * 128 + j);
        b.x *= dk; b.y *= dk; b.z *= dk; b.w *= dk;
        c.x *= dk; c.y *= dk; c.z *= dk; c.w *= dk;
        *(ushort4*)(X1 + (size_t)n * 256 + j)       = f2b4(a);
        *(ushort4*)(X1 + (size_t)n * 256 + 128 + j) = f2b4(b);
        *(ushort4*)(X2 + (size_t)n * 256 + 128 + j) = f2b4(c);
    } else if (gb < PREP_X_BLOCKS + PREP_W_BLOCKS) {
        const int i = ((gb - PREP_X_BLOCKS) * 256 + t) * 4;  // [0, 942080)
        if (i < 460 * 512) {
            *(ushort4*)(W1b + i) = f2b4(*(const float4*)(W1 + i));
        } else {
            const int k = i - 460 * 512;
            *(ushort4*)(W2b + k) = f2b4(*(const float4*)(W2 + k));
        }
    } else {
        const int g = (gb - PREP_X_BLOCKS - PREP_W_BLOCKS) * 256 + t;  // 8192
        const int c = g & 4095;
        const float* lw = (g < 4096) ? lw1 : lw2;
        const float* tw = (g < 4096) ? tw1 : tw2;
        unsigned short* Wp = (g < 4096) ? Wp1 : Wp2;
        const int ct = c >> 9, ks = (c >> 6) & 7, lane = c & 63;
        const int col = ct * 16 + (lane & 15);
        unsigned short* o = Wp + (size_t)c * 8;
        #pragma unroll
        for (int i = 0; i < 8; ++i) {
            const int k = ks * 32 + (lane >> 4) * 8 + i;
            const float v = (k < 128) ? lw[(size_t)k * 128 + col]
                                      : tw[(size_t)(k - 128) * 128 + col];
            o[i] = f2b(v);
        }
    }
}

// ---------------------------------------------------------------------------
// Aggregate v2 (proven 78 us): one wave per dst node, lane l handles k in
// {2l, 2l+1}. 1 dwordx4 meta (scalarized), 1 dword h (coalesced row),
// 1 dwordx4 W. 4 independent accumulator chains = the MLP win (k_agg3's
// balanced chunks w/ 1-deep pipeline regressed to 101; layer-fusion w/ LDS
// regressed to 113/layer). Writes agg*nnorm, full coverage, no memset needed.
// ---------------------------------------------------------------------------
__device__ __forceinline__ void agg_edge(
    const unsigned short* __restrict__ x,
    const unsigned short* __restrict__ Wb,
    const int4* __restrict__ sedge, int i,
    int woff, int l, float4& acc)
{
    const int4 e = sedge[i];
    const int src = __builtin_amdgcn_readfirstlane(e.x);
    const int typ = __builtin_amdgcn_readfirstlane(e.y);
    const float nr = __builtin_bit_cast(float, __builtin_amdgcn_readfirstlane(e.z));
    const unsigned hw = ((const unsigned*)(x + (size_t)src * 256))[l];
    const uint4 wv = *(const uint4*)(Wb + (size_t)typ * 512 + woff);
    const float h0 = b2f_lo(hw) * nr;
    const float h1 = b2f_hi(hw) * nr;
    acc.x += h0 * b2f_lo(wv.x) + h1 * b2f_lo(wv.z);
    acc.y += h0 * b2f_hi(wv.x) + h1 * b2f_hi(wv.z);
    acc.z += h0 * b2f_lo(wv.y) + h1 * b2f_lo(wv.w);
    acc.w += h0 * b2f_hi(wv.y) + h1 * b2f_hi(wv.w);
}

__global__ __launch_bounds__(256) void k_agg2(
    const unsigned short* __restrict__ x,    // [NN,256] bf16, cols 0..127 used
    const int4*  __restrict__ sedge,
    const int*   __restrict__ off,
    const unsigned short* __restrict__ Wb,   // [460,512] bf16
    const float* __restrict__ nnorm,
    float*       __restrict__ agg)           // [NN,128] = sum * nnorm
{
    const int l = threadIdx.x & 63;
    const int n = blockIdx.x * 4 + (threadIdx.x >> 6);
    const int beg = off[n], end = off[n + 1];
    const int woff = (l >> 1) * 16 + (l & 1) * 8;   // ushort offset in W row

    float4 a0 = {0,0,0,0}, a1 = {0,0,0,0}, a2 = {0,0,0,0}, a3 = {0,0,0,0};

    int i = beg;
    for (; i + 4 <= end; i += 4) {
        agg_edge(x, Wb, sedge, i,     woff, l, a0);
        agg_edge(x, Wb, sedge, i + 1, woff, l, a1);
        agg_edge(x, Wb, sedge, i + 2, woff, l, a2);
        agg_edge(x, Wb, sedge, i + 3, woff, l, a3);
    }
    for (; i < end; ++i) agg_edge(x, Wb, sedge, i, woff, l, a0);

    float4 s;
    s.x = (a0.x + a1.x) + (a2.x + a3.x);
    s.y = (a0.y + a1.y) + (a2.y + a3.y);
    s.z = (a0.z + a1.z) + (a2.z + a3.z);
    s.w = (a0.w + a1.w) + (a2.w + a3.w);
    s.x += __shfl_xor(s.x, 1);
    s.y += __shfl_xor(s.y, 1);
    s.z += __shfl_xor(s.z, 1);
    s.w += __shfl_xor(s.w, 1);

    const float nn = nnorm[n];
    const float e0 = (l & 1) ? s.z : s.x;
    const float e1 = (l & 1) ? s.w : s.y;
    float2* outp = (float2*)(agg + (size_t)n * DD + (l >> 1) * 4 + (l & 1) * 2);
    *outp = make_float2(e0 * nn, e1 * nn);
}

// ---------------------------------------------------------------------------
// Fused GEMM-combine via MFMA (agg already nnorm-scaled):
//   out[n] = agg[n] + (X[n] @ Wc) [+relu] ; optionally bf16 copy -> Xnext left
// LDS-staged coalesced epilogue (round-8 proven, ~19 us incl gap).
// ---------------------------------------------------------------------------
template<int ACT, int WRITE_NEXT>
__global__ __launch_bounds__(256) void combine_mfma(
    const float* __restrict__ agg,
    const unsigned short* __restrict__ X,     // [NN,256] bf16
    const unsigned short* __restrict__ Wp,    // packed 64KB
    float* __restrict__ out,                  // may alias agg
    unsigned short* __restrict__ Xnext)       // [NN,256] bf16 or nullptr
{
    const int t = threadIdx.x;
    const int l = t & 63;
    const int w = t >> 6;
    const int wr = w >> 1, wc = w & 1;
    const int l15 = l & 15, lhi = l >> 4;
    const int rowbase = blockIdx.x * 64 + wr * 32;

    f32x4 acc[2][4] = {};

    const int ar0 = min(rowbase + l15, NN - 1);
    const int ar1 = min(rowbase + 16 + l15, NN - 1);
    const unsigned short* a0p = X + (size_t)ar0 * 256 + lhi * 8;
    const unsigned short* a1p = X + (size_t)ar1 * 256 + lhi * 8;
    const unsigned short* bp  = Wp + (size_t)(wc * 4) * 8 * 512 + (size_t)l * 8;

    #pragma unroll
    for (int ks = 0; ks < 8; ++ks) {
        const short8 a0 = *(const short8*)(a0p + ks * 32);
        const short8 a1 = *(const short8*)(a1p + ks * 32);
        #pragma unroll
        for (int ct = 0; ct < 4; ++ct) {
            const short8 b = *(const short8*)(bp + (size_t)(ct * 8 + ks) * 512);
            acc[0][ct] = __builtin_amdgcn_mfma_f32_16x16x32_bf16(a0, b, acc[0][ct], 0, 0, 0);
            acc[1][ct] = __builtin_amdgcn_mfma_f32_16x16x32_bf16(a1, b, acc[1][ct], 0, 0, 0);
        }
    }

    // ---- LDS transpose: MFMA C-layout -> row-major ----
    __shared__ float cs[64][132];
    #pragma unroll
    for (int rg = 0; rg < 2; ++rg)
        #pragma unroll
        for (int ct = 0; ct < 4; ++ct)
            #pragma unroll
            for (int q = 0; q < 4; ++q)
                cs[wr * 32 + rg * 16 + lhi * 4 + q][wc * 64 + ct * 16 + l15]
                    = acc[rg][ct][q];
    __syncthreads();

    // ---- coalesced epilogue: thread = (row r, 4-col strip s) ----
    const int r = t >> 2;
    const int s = t & 3;
    const int grow = blockIdx.x * 64 + r;
    if (grow < NN) {
        const float* aggr = agg + (size_t)grow * DD;
        float*       outr = out + (size_t)grow * DD;
        #pragma unroll
        for (int i = 0; i < 8; ++i) {
            const int c = s * 4 + i * 16;
            const float4 a  = *(const float4*)(aggr + c);
            const float4 cc = *(const float4*)&cs[r][c];
            float4 v = make_float4(a.x + cc.x, a.y + cc.y, a.z + cc.z, a.w + cc.w);
            if (ACT) {
                v.x = fmaxf(v.x, 0.f); v.y = fmaxf(v.y, 0.f);
                v.z = fmaxf(v.z, 0.f); v.w = fmaxf(v.w, 0.f);
            }
            *(float4*)(outr + c) = v;
            if (WRITE_NEXT)
                *(ushort4*)(Xnext + (size_t)grow * 256 + c) = f2b4(v);
        }
    }
}

// ---------------------------------------------------------------------------
// Tier-2/3 fallback kernels
// ---------------------------------------------------------------------------
__device__ __forceinline__ float pick4(float4 v, int o) {
    float a = (o & 1) ? v.y : v.x;
    float b = (o & 1) ? v.w : v.z;
    return (o & 2) ? b : a;
}

__global__ __launch_bounds__(256) void k_agg_t2(
    const float* __restrict__ x, const int4* __restrict__ sedge,
    const int* __restrict__ off, const float* __restrict__ W,
    float* __restrict__ agg)
{
    const int lane = threadIdx.x & 63;
    const int n    = blockIdx.x * 4 + (threadIdx.x >> 6);
    const int beg = off[n], end = off[n + 1];
    float4 acca = make_float4(0.f, 0.f, 0.f, 0.f);
    float4 accb = make_float4(0.f, 0.f, 0.f, 0.f);
    for (int i = beg; i < end; ++i) {
        const int4 e = sedge[i];
        const float nr = __builtin_bit_cast(float, e.z);
        const float* wr = W + (size_t)e.y * 512 + 4 * lane;
        const float4 wa = *(const float4*)wr;
        const float4 wb = *(const float4*)(wr + 256);
        const float* hr = x + (size_t)e.x * DD;
        const float ha = hr[lane] * nr;
        const float hb = hr[64 + lane] * nr;
        acca.x += ha * wa.x; acca.y += ha * wa.y; acca.z += ha * wa.z; acca.w += ha * wa.w;
        accb.x += hb * wb.x; accb.y += hb * wb.y; accb.z += hb * wb.z; accb.w += hb * wb.w;
    }
    #pragma unroll
    for (int d = 1; d <= 2; d <<= 1) {
        acca.x += __shfl_xor(acca.x, d); acca.y += __shfl_xor(acca.y, d);
        acca.z += __shfl_xor(acca.z, d); acca.w += __shfl_xor(acca.w, d);
        accb.x += __shfl_xor(accb.x, d); accb.y += __shfl_xor(accb.y, d);
        accb.z += __shfl_xor(accb.z, d); accb.w += __shfl_xor(accb.w, d);
    }
    const int o = lane & 3;
    agg[(size_t)n * DD + lane]      = pick4(acca, o);
    agg[(size_t)n * DD + 64 + lane] = pick4(accb, o);
}

__global__ __launch_bounds__(256) void edge_msg(
    const float* __restrict__ x, const int* __restrict__ esrc,
    const int* __restrict__ edst, const int* __restrict__ etyp,
    const float* __restrict__ enorm, const float* __restrict__ W,
    float* __restrict__ agg)
{
    const int t  = threadIdx.x;
    const int le = t >> 7;
    const int j  = t & 127;
    const int e  = blockIdx.x * 2 + le;
    __shared__ float sh[2][DD];
    sh[le][j] = x[(size_t)esrc[e] * DD + j];
    __syncthreads();
    const int b = j >> 2, o = j & 3;
    const float* wr = W + (size_t)etyp[e] * 512 + b * 16 + o;
    const float4 hv = *(const float4*)&sh[le][b * 4];
    float m = hv.x * wr[0] + hv.y * wr[4] + hv.z * wr[8] + hv.w * wr[12];
    m *= enorm[e];
    atomicAdd(&agg[(size_t)edst[e] * DD + j], m);
}

template<int ACT>
__global__ __launch_bounds__(256) void combine(
    float* __restrict__ out, const float* __restrict__ x,
    const float* __restrict__ prev, const float* __restrict__ tdiff,
    const float* __restrict__ nnorm, const float* __restrict__ lw,
    const float* __restrict__ tw)
{
    const int t = threadIdx.x;
    const int j = t & 127;
    const int r = t >> 7;
    const int base = blockIdx.x * 8;
    __shared__ float sh[8][DD];
    __shared__ float sp[8][DD];
    #pragma unroll
    for (int q = 0; q < 4; ++q) {
        const int m = q * 2 + r;
        const int n = base + m;
        const float decay = __expf(-tdiff[n] * 0.1f);
        sh[m][j] = x[(size_t)n * DD + j];
        sp[m][j] = prev[(size_t)n * DD + j] * decay;
    }
    __syncthreads();
    float acc[4] = {0.f, 0.f, 0.f, 0.f};
    for (int k = 0; k < DD; k += 4) {
        float wl[4], wt[4];
        #pragma unroll
        for (int kk = 0; kk < 4; ++kk) {
            wl[kk] = lw[(size_t)(k + kk) * DD + j];
            wt[kk] = tw[(size_t)(k + kk) * DD + j];
        }
        #pragma unroll
        for (int q = 0; q < 4; ++q) {
            const int m = q * 2 + r;
            const float4 a = *(const float4*)&sh[m][k];
            const float4 p = *(const float4*)&sp[m][k];
            acc[q] += a.x * wl[0] + a.y * wl[1] + a.z * wl[2] + a.w * wl[3]
                    + p.x * wt[0] + p.y * wt[1] + p.z * wt[2] + p.w * wt[3];
        }
    }
    #pragma unroll
    for (int q = 0; q < 4; ++q) {
        const int m = q * 2 + r;
        const int n = base + m;
        float v = out[(size_t)n * DD + j] * nnorm[n] + acc[q];
        if (ACT) v = fmaxf(v, 0.f);
        out[(size_t)n * DD + j] = v;
    }
}

// ---------------------------------------------------------------------------
extern "C" void kernel_launch(void* const* d_in, const int* in_sizes, int n_in,
                              void* d_out, int out_size, void* d_ws, size_t ws_size,
                              hipStream_t stream) {
    const float* h     = (const float*)d_in[0];
    const float* fprev = (const float*)d_in[1];
    const float* sprev = (const float*)d_in[2];
    const float* tdiff = (const float*)d_in[3];
    const int*   esrc  = (const int*)d_in[4];
    const int*   edst  = (const int*)d_in[5];
    const int*   etyp  = (const int*)d_in[6];
    const float* enorm = (const float*)d_in[7];
    const float* nnorm = (const float*)d_in[8];
    const float* W1    = (const float*)d_in[9];
    const float* W2    = (const float*)d_in[10];
    const float* lw1   = (const float*)d_in[11];
    const float* lw2   = (const float*)d_in[12];
    const float* tw1   = (const float*)d_in[13];
    const float* tw2   = (const float*)d_in[14];

    float* h1 = (float*)d_out;
    float* h2 = h1 + (size_t)NN * DD;
    const size_t layer_bytes = (size_t)NN * DD * sizeof(float);

    // ---- carve workspace ----
    char* wsp = (char*)d_ws;
    int*   cnt   = (int*)wsp;  wsp += (size_t)NPAD * 4;
    int*   off   = (int*)wsp;  wsp += (size_t)NPAD * 4;
    int*   cur   = (int*)wsp;  wsp += (size_t)NPAD * 4;
    int*   bsum  = (int*)wsp;  wsp += 256 * 4;
    int4*  sedge = (int4*)wsp; wsp += (size_t)NE * 16;
    const size_t ws_sorted = (size_t)(wsp - (char*)d_ws);
    unsigned short* X1   = (unsigned short*)wsp; wsp += (size_t)NN * 256 * 2;
    unsigned short* X2   = (unsigned short*)wsp; wsp += (size_t)NN * 256 * 2;
    unsigned short* Wc1p = (unsigned short*)wsp; wsp += 4096 * 8 * 2;
    unsigned short* Wc2p = (unsigned short*)wsp; wsp += 4096 * 8 * 2;
    unsigned short* W1b  = (unsigned short*)wsp; wsp += (size_t)460 * 512 * 2;
    unsigned short* W2b  = (unsigned short*)wsp; wsp += (size_t)460 * 512 * 2;
    const size_t ws_full = (size_t)(wsp - (char*)d_ws);

    const int grid_mm = (NN + 63) / 64;     // 782

    if (ws_size >= ws_full) {
        // ---- dst-sort (shared by both layers) ----
        hipMemsetAsync(cnt, 0, (size_t)NPAD * 4, stream);
        k_hist   <<<NE / 256, 256, 0, stream>>>(edst, cnt);
        k_scan_a <<<NBLK_SCAN, 256, 0, stream>>>(cnt, bsum);
        k_scan_b <<<1, 256, 0, stream>>>(bsum);
        k_scan_c <<<NBLK_SCAN, 256, 0, stream>>>(cnt, bsum, off, cur);
        k_scatter<<<NE / 256, 256, 0, stream>>>(esrc, edst, etyp, enorm, cur, sedge);
        // ---- fused conversions (vectorized x4) ----
        k_prep<<<PREP_BLOCKS, 256, 0, stream>>>(
            h, fprev, sprev, tdiff, X1, X2,
            W1, W2, W1b, W2b, lw1, tw1, lw2, tw2, Wc1p, Wc2p);
        // ---- layer 1 ----
        k_agg2<<<NN / 4, 256, 0, stream>>>(X1, sedge, off, W1b, nnorm, h1);
        combine_mfma<0, 1><<<grid_mm, 256, 0, stream>>>(h1, X1, Wc1p, h1, X2);
        // ---- layer 2 ----
        k_agg2<<<NN / 4, 256, 0, stream>>>(X2, sedge, off, W2b, nnorm, h2);
        combine_mfma<1, 0><<<grid_mm, 256, 0, stream>>>(h2, X2, Wc2p, h2, nullptr);
    } else if (ws_size >= ws_sorted) {
        // tier 2: fp32 sorted path
        hipMemsetAsync(cnt, 0, (size_t)NPAD * 4, stream);
        k_hist   <<<NE / 256, 256, 0, stream>>>(edst, cnt);
        k_scan_a <<<NBLK_SCAN, 256, 0, stream>>>(cnt, bsum);
        k_scan_b <<<1, 256, 0, stream>>>(bsum);
        k_scan_c <<<NBLK_SCAN, 256, 0, stream>>>(cnt, bsum, off, cur);
        k_scatter<<<NE / 256, 256, 0, stream>>>(esrc, edst, etyp, enorm, cur, sedge);
        k_agg_t2<<<NN / 4, 256, 0, stream>>>(h, sedge, off, W1, h1);
        combine<0><<<NN / 8, 256, 0, stream>>>(h1, h, fprev, tdiff, nnorm, lw1, tw1);
        k_agg_t2<<<NN / 4, 256, 0, stream>>>(h1, sedge, off, W2, h2);
        combine<1><<<NN / 8, 256, 0, stream>>>(h2, h1, sprev, tdiff, nnorm, lw2, tw2);
    } else {
        // tier 3: atomic path
        hipMemsetAsync(h1, 0, layer_bytes, stream);
        edge_msg<<<NE / 2, 256, 0, stream>>>(h, esrc, edst, etyp, enorm, W1, h1);
        combine<0><<<NN / 8, 256, 0, stream>>>(h1, h, fprev, tdiff, nnorm, lw1, tw1);
        hipMemsetAsync(h2, 0, layer_bytes, stream);
        edge_msg<<<NE / 2, 256, 0, stream>>>(h1, esrc, edst, etyp, enorm, W2, h2);
        combine<1><<<NN / 8, 256, 0, stream>>>(h2, h1, sprev, tdiff, nnorm, lw2, tw2);
    }
}